// Round 4
// baseline (107.684 us; speedup 1.0000x reference)
//
#include <hip/hip_runtime.h>
#include <stdint.h>

typedef unsigned short u16;

#define B_ 8
#define C_ 64
#define H_ 128
#define W_ 128
#define OC_ 64
#define HO_ 128
#define WO_ 128
#define HWC_ (H_*W_*C_)   // elems per batch in NHWC

typedef __attribute__((ext_vector_type(8))) short short8;
typedef __attribute__((ext_vector_type(4))) float f32x4;
typedef __attribute__((ext_vector_type(2))) float f32x2;

__device__ __forceinline__ u16 f2bf(float f) {
  union { float f; uint32_t i; } v; v.f = f;
  uint32_t r = v.i + 0x7FFFu + ((v.i >> 16) & 1u);  // RNE
  return (u16)(r >> 16);
}
__device__ __forceinline__ uint32_t pkbf(float lo, float hi) {
  uint32_t r;
  asm("v_cvt_pk_bf16_f32 %0, %1, %2" : "=v"(r) : "v"(lo), "v"(hi));
  return r;
}

// ---- prep 1: weight [OC][C][3][3] f32 -> wk3 in MFMA A-fragment order ----
// flat = (((k*4 + m)*2 + kk)*64 + lane)*8 + j
//   oc = m*16 + (lane&15);  c = kk*32 + (lane>>4)*8 + j
__global__ void wprep_kernel(const float* __restrict__ w, u16* __restrict__ wk3) {
  const int idx = blockIdx.x * 256 + threadIdx.x;   // 144*256 = 36864 exact
  const int j    = idx & 7;
  const int lane = (idx >> 3) & 63;
  const int kk   = (idx >> 9) & 1;
  const int m    = (idx >> 10) & 3;
  const int k    = idx >> 12;
  const int oc = m*16 + (lane & 15);
  const int c  = kk*32 + (lane >> 4)*8 + j;
  wk3[idx] = f2bf(w[(oc*C_ + c)*9 + k]);
}

// ---- prep 2: input NCHW f32 -> NHWC bf16 ----
__global__ __launch_bounds__(256) void nhwc_kernel(const float* __restrict__ in,
                                                   u16* __restrict__ nhwc) {
  __shared__ float t[64][65];
  const int b = blockIdx.z, h = blockIdx.y, w0 = blockIdx.x * 64;
  const int tid = threadIdx.x;
  for (int idx = tid; idx < 64*64; idx += 256) {
    int c = idx >> 6, w = idx & 63;
    t[w][c] = in[((b*C_ + c)*H_ + h)*W_ + w0 + w];
  }
  __syncthreads();
  for (int idx = tid; idx < 64*64; idx += 256) {
    int w = idx >> 6, c = idx & 63;
    nhwc[((b*H_ + h)*W_ + w0 + w)*C_ + c] = f2bf(t[w][c]);
  }
}

__device__ __forceinline__ f32x2 up2(uint32_t g) {
  f32x2 r;
  r.x = __uint_as_float(g << 16);
  r.y = __uint_as_float(g & 0xFFFF0000u);
  return r;
}
__device__ __forceinline__ uint32_t blend2(uint32_t g00, uint32_t g01,
                                           uint32_t g10, uint32_t g11, float4 w) {
  f32x2 s = up2(g00)*w.x + up2(g01)*w.y + up2(g10)*w.z + up2(g11)*w.w;
  return pkbf(s.x, s.y);
}

// ---- main: 128px strip per block, 4 waves; each wave = 32px x 64oc,
//      B-fragments built IN REGISTERS (no col LDS, no k-loop barriers) ----
__global__ __launch_bounds__(256, 4) void mdconv_main(
    const float* __restrict__ offs, const float* __restrict__ mask,
    const float* __restrict__ bias, const u16* __restrict__ nhwc,
    const u16* __restrict__ wk3, float* __restrict__ out)
{
  __shared__ int2 pA[1152];          //  9216 B  {base, dx|dy<<16}
  __shared__ float4 pW[1152];        // 18432 B  corner weights (mask folded)

  const int tid = threadIdx.x;
  const int lane = tid & 63;
  const int wv = tid >> 6;
  const int b = blockIdx.z;
  const int p = blockIdx.y;

  // phase 1: per-(k,px) sampling params -> LDS (px = q here, 128-wide strip)
  for (int item = tid; item < 1152; item += 256) {
    const int k = item >> 7;
    const int q = item & 127;
    const int ky = k / 3, kx = k % 3;
    const float oy = offs[((b*18 + 2*k)*HO_ + p)*WO_ + q];
    const float ox = offs[((b*18 + 2*k + 1)*HO_ + p)*WO_ + q];
    const float mm = mask[((b*9 + k)*HO_ + p)*WO_ + q];
    const float py  = (float)(ky + p - 1) + oy;
    const float pxx = (float)(kx + q - 1) + ox;
    const float y0f = floorf(py), x0f = floorf(pxx);
    const int y0 = (int)y0f, x0 = (int)x0f;
    const int y1 = y0 + 1, x1 = x0 + 1;
    const float wy1 = py - y0f, wx1 = pxx - x0f;
    const float wy0 = 1.f - wy1, wx0 = 1.f - wx1;
    const bool vy0 = (y0 >= 0) & (y0 < H_);
    const bool vy1 = (y1 >= 0) & (y1 < H_);
    const bool vx0 = (x0 >= 0) & (x0 < W_);
    const bool vx1 = (x1 >= 0) & (x1 < W_);
    const float w00 = (vy0 & vx0) ? wy0*wx0*mm : 0.f;
    const float w01 = (vy0 & vx1) ? wy0*wx1*mm : 0.f;
    const float w10 = (vy1 & vx0) ? wy1*wx0*mm : 0.f;
    const float w11 = (vy1 & vx1) ? wy1*wx1*mm : 0.f;
    const int y0c = min(max(y0,0),H_-1), y1c = min(max(y1,0),H_-1);
    const int x0c = min(max(x0,0),W_-1), x1c = min(max(x1,0),W_-1);
    // invalid corners have zero weight, so clamped deltas are always safe
    const int dx = (x1c - x0c) * C_;        // 0 or 64
    const int dy = (y1c - y0c) * W_ * C_;   // 0 or 8192
    pA[item] = make_int2(b*HWC_ + (y0c*W_ + x0c)*C_, dx | (dy << 16));
    pW[item] = make_float4(w00, w01, w10, w11);
  }
  __syncthreads();   // the ONLY block-wide barrier

  f32x4 acc[4][2];
  #pragma unroll
  for (int m = 0; m < 4; ++m)
    #pragma unroll
    for (int n = 0; n < 2; ++n)
      acc[m][n] = (f32x4){0.f,0.f,0.f,0.f};

  const int pxl = lane & 15;         // px within 16-frag (B-frag col)
  const int c8  = (lane >> 4) * 8;   // channel chunk within 32 (B-frag k rows)

  #pragma unroll
  for (int k = 0; k < 9; ++k) {
    const int kbase = k*128 + wv*32;
    const int2  aA0 = pA[kbase + pxl];
    const int2  aA1 = pA[kbase + 16 + pxl];
    const float4 w0 = pW[kbase + pxl];
    const float4 w1 = pW[kbase + 16 + pxl];
    const int dx0 = aA0.y & 0xFFFF, dy0 = ((uint32_t)aA0.y) >> 16;
    const int dx1 = aA1.y & 0xFFFF, dy1 = ((uint32_t)aA1.y) >> 16;

    #pragma unroll
    for (int kk = 0; kk < 2; ++kk) {
      // A-fragments for all 4 oc-blocks (same for every lane group; L2-hit)
      const u16* wg = wk3 + ((k*4)*2 + kk)*512 + lane*8;
      const short8 am0 = *(const short8*)(wg);
      const short8 am1 = *(const short8*)(wg + 1024);
      const short8 am2 = *(const short8*)(wg + 2048);
      const short8 am3 = *(const short8*)(wg + 3072);

      #pragma unroll
      for (int n = 0; n < 2; ++n) {
        const int base = (n == 0) ? aA0.x : aA1.x;
        const int dx   = (n == 0) ? dx0 : dx1;
        const int dy   = (n == 0) ? dy0 : dy1;
        const float4 w = (n == 0) ? w0 : w1;
        const u16* s = nhwc + base + kk*32 + c8;
        const uint4 g00 = *(const uint4*)(s);
        const uint4 g01 = *(const uint4*)(s + dx);
        const uint4 g10 = *(const uint4*)(s + dy);
        const uint4 g11 = *(const uint4*)(s + dy + dx);
        union { uint32_t u[4]; short8 s8; } bf;
        bf.u[0] = blend2(g00.x, g01.x, g10.x, g11.x, w);
        bf.u[1] = blend2(g00.y, g01.y, g10.y, g11.y, w);
        bf.u[2] = blend2(g00.z, g01.z, g10.z, g11.z, w);
        bf.u[3] = blend2(g00.w, g01.w, g10.w, g11.w, w);
        acc[0][n] = __builtin_amdgcn_mfma_f32_16x16x32_bf16(am0, bf.s8, acc[0][n], 0, 0, 0);
        acc[1][n] = __builtin_amdgcn_mfma_f32_16x16x32_bf16(am1, bf.s8, acc[1][n], 0, 0, 0);
        acc[2][n] = __builtin_amdgcn_mfma_f32_16x16x32_bf16(am2, bf.s8, acc[2][n], 0, 0, 0);
        acc[3][n] = __builtin_amdgcn_mfma_f32_16x16x32_bf16(am3, bf.s8, acc[3][n], 0, 0, 0);
      }
    }
  }

  // epilogue: C/D layout col=lane&15 (px), row=(lane>>4)*4+j (oc)
  #pragma unroll
  for (int m = 0; m < 4; ++m) {
    const int ocr = m*16 + (lane >> 4)*4;
    const float4 b4 = *(const float4*)(bias + ocr);
    #pragma unroll
    for (int n = 0; n < 2; ++n) {
      const int q = wv*32 + n*16 + pxl;
      #pragma unroll
      for (int j = 0; j < 4; ++j) {
        out[((b*OC_ + ocr + j)*HO_ + p)*WO_ + q] = acc[m][n][j] + ((const float*)&b4)[j];
      }
    }
  }
}

extern "C" void kernel_launch(void* const* d_in, const int* in_sizes, int n_in,
                              void* d_out, int out_size, void* d_ws, size_t ws_size,
                              hipStream_t stream) {
  const float* input  = (const float*)d_in[0];
  const float* offset = (const float*)d_in[1];
  const float* mask   = (const float*)d_in[2];
  const float* weight = (const float*)d_in[3];
  const float* bias   = (const float*)d_in[4];
  float* out = (float*)d_out;

  u16* nhwc = (u16*)d_ws;                              // 16 MB
  u16* wk3  = nhwc + (size_t)B_*H_*W_*C_;              // 72 KB

  hipLaunchKernelGGL(wprep_kernel, dim3(144), dim3(256), 0, stream, weight, wk3);
  hipLaunchKernelGGL(nhwc_kernel, dim3(2, 128, 8), dim3(256), 0, stream, input, nhwc);
  hipLaunchKernelGGL(mdconv_main, dim3(1, 128, 8), dim3(256), 0, stream,
                     offset, mask, bias, nhwc, wk3, out);
}

// Round 5
// 76.076 us; speedup vs baseline: 1.4155x; 1.4155x over previous
//
#include <hip/hip_runtime.h>
#include <stdint.h>

typedef unsigned short u16;

#define B_ 8
#define C_ 64
#define H_ 128
#define W_ 128
#define OC_ 64
#define HO_ 128
#define WO_ 128
#define HWC_ (H_*W_*C_)   // elems per batch in NHWC
#define PADW 72           // padded tile row (bf16): 144B, 16B-aligned

typedef __attribute__((ext_vector_type(8))) short short8;
typedef __attribute__((ext_vector_type(4))) float f32x4;
typedef __attribute__((ext_vector_type(2))) float f32x2;

__device__ __forceinline__ u16 f2bf(float f) {
  union { float f; uint32_t i; } v; v.f = f;
  uint32_t r = v.i + 0x7FFFu + ((v.i >> 16) & 1u);  // RNE
  return (u16)(r >> 16);
}
__device__ __forceinline__ uint32_t pkbf(float lo, float hi) {
  uint32_t r;
  asm("v_cvt_pk_bf16_f32 %0, %1, %2" : "=v"(r) : "v"(lo), "v"(hi));
  return r;
}
__device__ __forceinline__ f32x2 up2(uint32_t g) {
  f32x2 r;
  r.x = __uint_as_float(g << 16);
  r.y = __uint_as_float(g & 0xFFFF0000u);
  return r;
}
__device__ __forceinline__ uint32_t blend2(uint32_t g00, uint32_t g01,
                                           uint32_t g10, uint32_t g11, float4 w) {
  f32x2 s = up2(g00)*w.x + up2(g01)*w.y + up2(g10)*w.z + up2(g11)*w.w;
  return pkbf(s.x, s.y);
}

// ---- prep 1: weight [OC][C][3][3] f32 -> wk2 in MFMA A-fragment order ----
// wk2 flat index = (((k*2 + wr)*2 + m)*2 + kk)*512 + lane*8 + j
//   oc = wr*32 + m*16 + (lane&15);  c = kk*32 + (lane>>4)*8 + j
__global__ void wprep_kernel(const float* __restrict__ w, u16* __restrict__ wk2) {
  const int idx = blockIdx.x * 256 + threadIdx.x;   // 144*256 = 36864 exact
  const int j    = idx & 7;
  const int lane = (idx >> 3) & 63;
  const int kk   = (idx >> 9) & 1;
  const int m    = (idx >> 10) & 1;
  const int wr   = (idx >> 11) & 1;
  const int k    = idx >> 12;
  const int oc = wr*32 + m*16 + (lane & 15);
  const int c  = kk*32 + (lane >> 4)*8 + j;
  wk2[idx] = f2bf(w[(oc*C_ + c)*9 + k]);
}

// ---- prep 2: input NCHW f32 -> NHWC bf16 ----
__global__ __launch_bounds__(256) void nhwc_kernel(const float* __restrict__ in,
                                                   u16* __restrict__ nhwc) {
  __shared__ float t[64][65];
  const int b = blockIdx.z, h = blockIdx.y, w0 = blockIdx.x * 64;
  const int tid = threadIdx.x;
  for (int idx = tid; idx < 64*64; idx += 256) {
    int c = idx >> 6, w = idx & 63;
    t[w][c] = in[((b*C_ + c)*H_ + h)*W_ + w0 + w];
  }
  __syncthreads();
  for (int idx = tid; idx < 64*64; idx += 256) {
    int w = idx >> 6, c = idx & 63;
    nhwc[((b*H_ + h)*W_ + w0 + w)*C_ + c] = f2bf(t[w][c]);
  }
}

// ---- main: 64px strip x 64oc per block, 4 waves; wave = 32px x 32oc with a
//      PRIVATE LDS transpose tile -> ZERO barriers in the k-loop ----
__global__ __launch_bounds__(256, 4) void mdconv_main(
    const float* __restrict__ offs, const float* __restrict__ mask,
    const float* __restrict__ bias, const u16* __restrict__ nhwc,
    const u16* __restrict__ wk2, float* __restrict__ out)
{
  __shared__ u16 tlds[4][32*PADW];  // 18432 B : per-wave private B-tiles
  __shared__ int2 pA[576];          //  4608 B  {base, dx|dy<<16}
  __shared__ float4 pW[576];        //  9216 B  corner weights (mask folded)

  const int tid = threadIdx.x;
  const int lane = tid & 63;
  const int wv = tid >> 6;
  const int b = blockIdx.z;
  const int p = blockIdx.y;
  const int q0 = blockIdx.x * 64;

  // phase 1: per-(k,px) sampling params -> LDS
  for (int item = tid; item < 576; item += 256) {
    const int k = item >> 6;
    const int px = item & 63;
    const int q = q0 + px;
    const int ky = k / 3, kx = k % 3;
    const float oy = offs[((b*18 + 2*k)*HO_ + p)*WO_ + q];
    const float ox = offs[((b*18 + 2*k + 1)*HO_ + p)*WO_ + q];
    const float mm = mask[((b*9 + k)*HO_ + p)*WO_ + q];
    const float py  = (float)(ky + p - 1) + oy;
    const float pxx = (float)(kx + q - 1) + ox;
    const float y0f = floorf(py), x0f = floorf(pxx);
    const int y0 = (int)y0f, x0 = (int)x0f;
    const int y1 = y0 + 1, x1 = x0 + 1;
    const float wy1 = py - y0f, wx1 = pxx - x0f;
    const float wy0 = 1.f - wy1, wx0 = 1.f - wx1;
    const bool vy0 = (y0 >= 0) & (y0 < H_);
    const bool vy1 = (y1 >= 0) & (y1 < H_);
    const bool vx0 = (x0 >= 0) & (x0 < W_);
    const bool vx1 = (x1 >= 0) & (x1 < W_);
    const float w00 = (vy0 & vx0) ? wy0*wx0*mm : 0.f;
    const float w01 = (vy0 & vx1) ? wy0*wx1*mm : 0.f;
    const float w10 = (vy1 & vx0) ? wy1*wx0*mm : 0.f;
    const float w11 = (vy1 & vx1) ? wy1*wx1*mm : 0.f;
    const int y0c = min(max(y0,0),H_-1), y1c = min(max(y1,0),H_-1);
    const int x0c = min(max(x0,0),W_-1), x1c = min(max(x1,0),W_-1);
    // invalid corners have zero weight, so clamped deltas are always safe
    const int dx = (x1c - x0c) * C_;        // 0 or 64
    const int dy = (y1c - y0c) * W_ * C_;   // 0 or 8192
    pA[item] = make_int2(b*HWC_ + (y0c*W_ + x0c)*C_, dx | (dy << 16));
    pW[item] = make_float4(w00, w01, w10, w11);
  }
  __syncthreads();   // the ONLY block-wide barrier

  f32x4 acc00 = {0.f,0.f,0.f,0.f};
  f32x4 acc01 = acc00, acc10 = acc00, acc11 = acc00;
  const int wr = wv >> 1, wc = wv & 1;
  const int pxg = lane >> 3;         // px within 8-group
  const int c8  = (lane & 7) * 8;    // channel chunk (16B)

  u16* tw = &tlds[wv][0];
  const u16* cb = &tlds[wv][(lane & 15)*PADW + (lane >> 4)*8];

#pragma unroll
  for (int k = 0; k < 9; ++k) {
    // A-fragments from global (L2-resident; proven pattern from R2/R3)
    const u16* wg = wk2 + (k*2 + wr)*2048 + lane*8;
    const short8 a00 = *(const short8*)(wg);
    const short8 a01 = *(const short8*)(wg + 512);
    const short8 a10 = *(const short8*)(wg + 1024);
    const short8 a11 = *(const short8*)(wg + 1536);

    // gathers: 4 groups of 8px; 8 consecutive lanes cover 128B per corner
    uint4 G0[4], G1[4], G2[4], G3[4];
    float4 W0, W1, W2, W3;
#define LOADG(g_, Gv, Wv) { \
      const int pi = k*64 + wc*32 + (g_)*8 + pxg; \
      const int2 aa = pA[pi]; Wv = pW[pi]; \
      const u16* s = nhwc + aa.x + c8; \
      const int dx = aa.y & 0xFFFF, dy = ((uint32_t)aa.y) >> 16; \
      Gv[0] = *(const uint4*)(s); \
      Gv[1] = *(const uint4*)(s + dx); \
      Gv[2] = *(const uint4*)(s + dy); \
      Gv[3] = *(const uint4*)(s + dy + dx); }
    LOADG(0, G0, W0); LOADG(1, G1, W1); LOADG(2, G2, W2); LOADG(3, G3, W3);
#undef LOADG

#define BW(g_, Gv, Wv) { \
      uint4 r; \
      r.x = blend2(Gv[0].x, Gv[1].x, Gv[2].x, Gv[3].x, Wv); \
      r.y = blend2(Gv[0].y, Gv[1].y, Gv[2].y, Gv[3].y, Wv); \
      r.z = blend2(Gv[0].z, Gv[1].z, Gv[2].z, Gv[3].z, Wv); \
      r.w = blend2(Gv[0].w, Gv[1].w, Gv[2].w, Gv[3].w, Wv); \
      *(uint4*)(tw + ((g_)*8 + pxg)*PADW + c8) = r; }
    BW(0, G0, W0); BW(1, G1, W1); BW(2, G2, W2); BW(3, G3, W3);
#undef BW

    // B-fragments from this wave's private tile (in-order DS => no barrier)
    const short8 b00 = *(const short8*)(cb);
    const short8 b01 = *(const short8*)(cb + 32);
    const short8 b10 = *(const short8*)(cb + 16*PADW);
    const short8 b11 = *(const short8*)(cb + 16*PADW + 32);
    acc00 = __builtin_amdgcn_mfma_f32_16x16x32_bf16(a00, b00, acc00, 0, 0, 0);
    acc00 = __builtin_amdgcn_mfma_f32_16x16x32_bf16(a01, b01, acc00, 0, 0, 0);
    acc01 = __builtin_amdgcn_mfma_f32_16x16x32_bf16(a00, b10, acc01, 0, 0, 0);
    acc01 = __builtin_amdgcn_mfma_f32_16x16x32_bf16(a01, b11, acc01, 0, 0, 0);
    acc10 = __builtin_amdgcn_mfma_f32_16x16x32_bf16(a10, b00, acc10, 0, 0, 0);
    acc10 = __builtin_amdgcn_mfma_f32_16x16x32_bf16(a11, b01, acc10, 0, 0, 0);
    acc11 = __builtin_amdgcn_mfma_f32_16x16x32_bf16(a10, b10, acc11, 0, 0, 0);
    acc11 = __builtin_amdgcn_mfma_f32_16x16x32_bf16(a11, b11, acc11, 0, 0, 0);
  }

  // epilogue: C/D layout col=lane&15 (px), row=(lane>>4)*4+j (oc)
  const int qc = q0 + wc*32 + (lane & 15);
  const int ocr = wr*32 + (lane >> 4)*4;
  #pragma unroll
  for (int m = 0; m < 2; ++m) {
    #pragma unroll
    for (int n = 0; n < 2; ++n) {
      const f32x4 a = (m==0) ? (n==0 ? acc00 : acc01) : (n==0 ? acc10 : acc11);
      #pragma unroll
      for (int j = 0; j < 4; ++j) {
        const int oc = ocr + m*16 + j;
        out[((b*OC_ + oc)*HO_ + p)*WO_ + qc + n*16] = a[j] + bias[oc];
      }
    }
  }
}

extern "C" void kernel_launch(void* const* d_in, const int* in_sizes, int n_in,
                              void* d_out, int out_size, void* d_ws, size_t ws_size,
                              hipStream_t stream) {
  const float* input  = (const float*)d_in[0];
  const float* offset = (const float*)d_in[1];
  const float* mask   = (const float*)d_in[2];
  const float* weight = (const float*)d_in[3];
  const float* bias   = (const float*)d_in[4];
  float* out = (float*)d_out;

  u16* nhwc = (u16*)d_ws;                              // 16 MB
  u16* wk2  = nhwc + (size_t)B_*H_*W_*C_;              // 72 KB

  hipLaunchKernelGGL(wprep_kernel, dim3(144), dim3(256), 0, stream, weight, wk2);
  hipLaunchKernelGGL(nhwc_kernel, dim3(2, 128, 8), dim3(256), 0, stream, input, nhwc);
  hipLaunchKernelGGL(mdconv_main, dim3(2, 128, 8), dim3(256), 0, stream,
                     offset, mask, bias, nhwc, wk2, out);
}

// Round 6
// 57.535 us; speedup vs baseline: 1.8716x; 1.3223x over previous
//
#include <hip/hip_runtime.h>
#include <stdint.h>

typedef unsigned short u16;

#define B_ 8
#define C_ 64
#define H_ 128
#define W_ 128
#define OC_ 64
#define HO_ 128
#define WO_ 128
#define HWC_ (H_*W_*C_)   // elems per batch in NHWC
#define PADW 72           // padded clds row (f16): 144B, 16B-aligned

typedef __attribute__((ext_vector_type(8))) _Float16 f16x8;
typedef __attribute__((ext_vector_type(2))) _Float16 h2;
typedef __attribute__((ext_vector_type(4))) float f32x4;

__device__ __forceinline__ u16 f2h(float f) {
  union { _Float16 h; u16 u; } c; c.h = (_Float16)f; return c.u;
}
__device__ __forceinline__ uint32_t pkh2(float f) {   // (h,h) packed pair
  union { _Float16 h[2]; uint32_t u; } c;
  const _Float16 h = (_Float16)f;
  c.h[0] = h; c.h[1] = h; return c.u;
}

// ---- prep 1: weight [OC][C][3][3] f32 -> wk2 in MFMA A-fragment order (f16) ----
// wk2 flat index = (((k*2 + wr)*2 + m)*2 + kk)*512 + lane*8 + j
//   oc = wr*32 + m*16 + (lane&15);  c = kk*32 + (lane>>4)*8 + j
__global__ void wprep_kernel(const float* __restrict__ w, u16* __restrict__ wk2) {
  const int idx = blockIdx.x * 256 + threadIdx.x;   // 144*256 = 36864 exact
  const int j    = idx & 7;
  const int lane = (idx >> 3) & 63;
  const int kk   = (idx >> 9) & 1;
  const int m    = (idx >> 10) & 1;
  const int wr   = (idx >> 11) & 1;
  const int k    = idx >> 12;
  const int oc = wr*32 + m*16 + (lane & 15);
  const int c  = kk*32 + (lane >> 4)*8 + j;
  wk2[idx] = f2h(w[(oc*C_ + c)*9 + k]);
}

// ---- prep 2: input NCHW f32 -> NHWC f16 ----
__global__ __launch_bounds__(256) void nhwc_kernel(const float* __restrict__ in,
                                                   u16* __restrict__ nhwc) {
  __shared__ float t[64][65];
  const int b = blockIdx.z, h = blockIdx.y, w0 = blockIdx.x * 64;
  const int tid = threadIdx.x;
  for (int idx = tid; idx < 64*64; idx += 256) {
    int c = idx >> 6, w = idx & 63;
    t[w][c] = in[((b*C_ + c)*H_ + h)*W_ + w0 + w];
  }
  __syncthreads();
  for (int idx = tid; idx < 64*64; idx += 256) {
    int w = idx >> 6, c = idx & 63;
    nhwc[((b*H_ + h)*W_ + w0 + w)*C_ + c] = f2h(t[w][c]);
  }
}

// packed-f16 bilinear blend: 2 channels per call, 4 v_pk_fma_f16
__device__ __forceinline__ uint32_t blendh(uint32_t g00, uint32_t g01,
                                           uint32_t g10, uint32_t g11, uint4 w) {
  h2 s = __builtin_bit_cast(h2, g00) * __builtin_bit_cast(h2, w.x)
       + __builtin_bit_cast(h2, g01) * __builtin_bit_cast(h2, w.y)
       + __builtin_bit_cast(h2, g10) * __builtin_bit_cast(h2, w.z)
       + __builtin_bit_cast(h2, g11) * __builtin_bit_cast(h2, w.w);
  return __builtin_bit_cast(uint32_t, s);
}

// ---- main: 64px strip x 64oc per block, 4 waves, f16 MFMA (R2 structure) ----
__global__ __launch_bounds__(256, 4) void mdconv_main(
    const float* __restrict__ offs, const float* __restrict__ mask,
    const float* __restrict__ bias, const u16* __restrict__ nhwc,
    const u16* __restrict__ wk2, float* __restrict__ out)
{
  __shared__ u16 clds[64*PADW];     // 9216 B
  __shared__ int2 pA[576];          // 4608 B  {base, dx|dy<<16}
  __shared__ uint4 pW[576];         // 9216 B  corner weights, packed (h,h) f16x2

  const int tid = threadIdx.x;
  const int lane = tid & 63;
  const int wv = tid >> 6;
  const int b = blockIdx.z;
  const int p = blockIdx.y;
  const int q0 = blockIdx.x * 64;

  // phase 1: per-(k,px) sampling params -> LDS
  for (int item = tid; item < 576; item += 256) {
    const int k = item >> 6;
    const int px = item & 63;
    const int q = q0 + px;
    const int ky = k / 3, kx = k % 3;
    const float oy = offs[((b*18 + 2*k)*HO_ + p)*WO_ + q];
    const float ox = offs[((b*18 + 2*k + 1)*HO_ + p)*WO_ + q];
    const float mm = mask[((b*9 + k)*HO_ + p)*WO_ + q];
    const float py  = (float)(ky + p - 1) + oy;
    const float pxx = (float)(kx + q - 1) + ox;
    const float y0f = floorf(py), x0f = floorf(pxx);
    const int y0 = (int)y0f, x0 = (int)x0f;
    const int y1 = y0 + 1, x1 = x0 + 1;
    const float wy1 = py - y0f, wx1 = pxx - x0f;
    const float wy0 = 1.f - wy1, wx0 = 1.f - wx1;
    const bool vy0 = (y0 >= 0) & (y0 < H_);
    const bool vy1 = (y1 >= 0) & (y1 < H_);
    const bool vx0 = (x0 >= 0) & (x0 < W_);
    const bool vx1 = (x1 >= 0) & (x1 < W_);
    const float w00 = (vy0 & vx0) ? wy0*wx0*mm : 0.f;
    const float w01 = (vy0 & vx1) ? wy0*wx1*mm : 0.f;
    const float w10 = (vy1 & vx0) ? wy1*wx0*mm : 0.f;
    const float w11 = (vy1 & vx1) ? wy1*wx1*mm : 0.f;
    const int y0c = min(max(y0,0),H_-1), y1c = min(max(y1,0),H_-1);
    const int x0c = min(max(x0,0),W_-1), x1c = min(max(x1,0),W_-1);
    // invalid corners have zero weight, so clamped deltas are always safe
    const int dx = (x1c - x0c) * C_;        // 0 or 64
    const int dy = (y1c - y0c) * W_ * C_;   // 0 or 8192
    pA[item] = make_int2(b*HWC_ + (y0c*W_ + x0c)*C_, dx | (dy << 16));
    pW[item] = make_uint4(pkh2(w00), pkh2(w01), pkh2(w10), pkh2(w11));
  }
  __syncthreads();

  f32x4 acc00 = {0.f,0.f,0.f,0.f};
  f32x4 acc01 = acc00, acc10 = acc00, acc11 = acc00;
  const int wr = wv >> 1, wc = wv & 1;
  const int px0 = tid >> 3;          // 0..31 (second item: +32)
  const int c8 = (tid & 7) * 8;      // channel chunk start

  for (int k = 0; k < 9; ++k) {
    // A-fragments straight from global (L2-resident, coalesced); used after barrier
    const u16* wg = wk2 + (k*2 + wr)*2048 + lane*8;
    const f16x8 a00 = *(const f16x8*)(wg);
    const f16x8 a01 = *(const f16x8*)(wg + 512);
    const f16x8 a10 = *(const f16x8*)(wg + 1024);
    const f16x8 a11 = *(const f16x8*)(wg + 1536);

    // col build: 2 items/thread, 8 independent 16B gathers in flight
    {
      const int piA = k*64 + px0, piB = piA + 32;
      const int2 aA = pA[piA];
      const int2 aB = pA[piB];
      const uint4 wA = pW[piA];
      const uint4 wB = pW[piB];
      const u16* sA = nhwc + aA.x + c8;
      const u16* sB = nhwc + aB.x + c8;
      const int dxA = aA.y & 0xFFFF, dyA = ((uint32_t)aA.y) >> 16;
      const int dxB = aB.y & 0xFFFF, dyB = ((uint32_t)aB.y) >> 16;
      const uint4 gA00 = *(const uint4*)(sA);
      const uint4 gA01 = *(const uint4*)(sA + dxA);
      const uint4 gA10 = *(const uint4*)(sA + dyA);
      const uint4 gA11 = *(const uint4*)(sA + dyA + dxA);
      const uint4 gB00 = *(const uint4*)(sB);
      const uint4 gB01 = *(const uint4*)(sB + dxB);
      const uint4 gB10 = *(const uint4*)(sB + dyB);
      const uint4 gB11 = *(const uint4*)(sB + dyB + dxB);
      uint4 rA, rB;
      rA.x = blendh(gA00.x, gA01.x, gA10.x, gA11.x, wA);
      rA.y = blendh(gA00.y, gA01.y, gA10.y, gA11.y, wA);
      rA.z = blendh(gA00.z, gA01.z, gA10.z, gA11.z, wA);
      rA.w = blendh(gA00.w, gA01.w, gA10.w, gA11.w, wA);
      rB.x = blendh(gB00.x, gB01.x, gB10.x, gB11.x, wB);
      rB.y = blendh(gB00.y, gB01.y, gB10.y, gB11.y, wB);
      rB.z = blendh(gB00.z, gB01.z, gB10.z, gB11.z, wB);
      rB.w = blendh(gB00.w, gB01.w, gB10.w, gB11.w, wB);
      *(uint4*)(&clds[px0*PADW + c8]) = rA;
      *(uint4*)(&clds[(px0+32)*PADW + c8]) = rB;
    }
    __syncthreads();

    const f16x8 b00 = *(const f16x8*)(&clds[(wc*32 + (lane & 15))*PADW + (lane >> 4)*8]);
    const f16x8 b01 = *(const f16x8*)(&clds[(wc*32 + (lane & 15))*PADW + (lane >> 4)*8 + 32]);
    const f16x8 b10 = *(const f16x8*)(&clds[(wc*32 + 16 + (lane & 15))*PADW + (lane >> 4)*8]);
    const f16x8 b11 = *(const f16x8*)(&clds[(wc*32 + 16 + (lane & 15))*PADW + (lane >> 4)*8 + 32]);
    acc00 = __builtin_amdgcn_mfma_f32_16x16x32_f16(a00, b00, acc00, 0, 0, 0);
    acc00 = __builtin_amdgcn_mfma_f32_16x16x32_f16(a01, b01, acc00, 0, 0, 0);
    acc01 = __builtin_amdgcn_mfma_f32_16x16x32_f16(a00, b10, acc01, 0, 0, 0);
    acc01 = __builtin_amdgcn_mfma_f32_16x16x32_f16(a01, b11, acc01, 0, 0, 0);
    acc10 = __builtin_amdgcn_mfma_f32_16x16x32_f16(a10, b00, acc10, 0, 0, 0);
    acc10 = __builtin_amdgcn_mfma_f32_16x16x32_f16(a11, b01, acc10, 0, 0, 0);
    acc11 = __builtin_amdgcn_mfma_f32_16x16x32_f16(a10, b10, acc11, 0, 0, 0);
    acc11 = __builtin_amdgcn_mfma_f32_16x16x32_f16(a11, b11, acc11, 0, 0, 0);
    if (k < 8) __syncthreads();
  }

  // epilogue: C/D layout col=lane&15 (px), row=(lane>>4)*4+j (oc)
  const int qc = q0 + wc*32 + (lane & 15);
  const int ocr = wr*32 + (lane >> 4)*4;
  #pragma unroll
  for (int m = 0; m < 2; ++m) {
    #pragma unroll
    for (int n = 0; n < 2; ++n) {
      const f32x4 a = (m==0) ? (n==0 ? acc00 : acc01) : (n==0 ? acc10 : acc11);
      #pragma unroll
      for (int j = 0; j < 4; ++j) {
        const int oc = ocr + m*16 + j;
        out[((b*OC_ + oc)*HO_ + p)*WO_ + qc + n*16] = a[j] + bias[oc];
      }
    }
  }
}

extern "C" void kernel_launch(void* const* d_in, const int* in_sizes, int n_in,
                              void* d_out, int out_size, void* d_ws, size_t ws_size,
                              hipStream_t stream) {
  const float* input  = (const float*)d_in[0];
  const float* offset = (const float*)d_in[1];
  const float* mask   = (const float*)d_in[2];
  const float* weight = (const float*)d_in[3];
  const float* bias   = (const float*)d_in[4];
  float* out = (float*)d_out;

  u16* nhwc = (u16*)d_ws;                              // 16 MB
  u16* wk2  = nhwc + (size_t)B_*H_*W_*C_;              // 72 KB

  hipLaunchKernelGGL(wprep_kernel, dim3(144), dim3(256), 0, stream, weight, wk2);
  hipLaunchKernelGGL(nhwc_kernel, dim3(2, 128, 8), dim3(256), 0, stream, input, nhwc);
  hipLaunchKernelGGL(mdconv_main, dim3(2, 128, 8), dim3(256), 0, stream,
                     offset, mask, bias, nhwc, wk2, out);
}

// Round 7
// 55.873 us; speedup vs baseline: 1.9273x; 1.0297x over previous
//
#include <hip/hip_runtime.h>
#include <stdint.h>

typedef unsigned short u16;

#define B_ 8
#define C_ 64
#define H_ 128
#define W_ 128
#define OC_ 64
#define HO_ 128
#define WO_ 128
#define HWC_ (H_*W_*C_)   // elems per batch in NHWC
#define PADW 72           // padded clds row (f16): 144B, 16B-aligned

typedef __attribute__((ext_vector_type(8))) _Float16 f16x8;
typedef __attribute__((ext_vector_type(2))) _Float16 h2;
typedef __attribute__((ext_vector_type(4))) float f32x4;

__device__ __forceinline__ u16 f2h(float f) {
  union { _Float16 h; u16 u; } c; c.h = (_Float16)f; return c.u;
}
__device__ __forceinline__ uint32_t pkh2(float f) {   // (h,h) packed pair
  union { _Float16 h[2]; uint32_t u; } c;
  const _Float16 h = (_Float16)f;
  c.h[0] = h; c.h[1] = h; return c.u;
}

// ---- prep 1: weight [OC][C][3][3] f32 -> wk2 in MFMA A-fragment order (f16) ----
// wk2 flat index = (((k*2 + wr)*2 + m)*2 + kk)*512 + lane*8 + j
//   oc = wr*32 + m*16 + (lane&15);  c = kk*32 + (lane>>4)*8 + j
__global__ void wprep_kernel(const float* __restrict__ w, u16* __restrict__ wk2) {
  const int idx = blockIdx.x * 256 + threadIdx.x;   // 144*256 = 36864 exact
  const int j    = idx & 7;
  const int lane = (idx >> 3) & 63;
  const int kk   = (idx >> 9) & 1;
  const int m    = (idx >> 10) & 1;
  const int wr   = (idx >> 11) & 1;
  const int k    = idx >> 12;
  const int oc = wr*32 + m*16 + (lane & 15);
  const int c  = kk*32 + (lane >> 4)*8 + j;
  wk2[idx] = f2h(w[(oc*C_ + c)*9 + k]);
}

// ---- prep 2: input NCHW f32 -> NHWC f16 ----
__global__ __launch_bounds__(256) void nhwc_kernel(const float* __restrict__ in,
                                                   u16* __restrict__ nhwc) {
  __shared__ float t[64][65];
  const int b = blockIdx.z, h = blockIdx.y, w0 = blockIdx.x * 64;
  const int tid = threadIdx.x;
  for (int idx = tid; idx < 64*64; idx += 256) {
    int c = idx >> 6, w = idx & 63;
    t[w][c] = in[((b*C_ + c)*H_ + h)*W_ + w0 + w];
  }
  __syncthreads();
  for (int idx = tid; idx < 64*64; idx += 256) {
    int w = idx >> 6, c = idx & 63;
    nhwc[((b*H_ + h)*W_ + w0 + w)*C_ + c] = f2h(t[w][c]);
  }
}

// packed-f16 bilinear blend: 2 channels per call, 4 v_pk_fma_f16
__device__ __forceinline__ uint32_t blendh(uint32_t g00, uint32_t g01,
                                           uint32_t g10, uint32_t g11, uint4 w) {
  h2 s = __builtin_bit_cast(h2, g00) * __builtin_bit_cast(h2, w.x)
       + __builtin_bit_cast(h2, g01) * __builtin_bit_cast(h2, w.y)
       + __builtin_bit_cast(h2, g10) * __builtin_bit_cast(h2, w.z)
       + __builtin_bit_cast(h2, g11) * __builtin_bit_cast(h2, w.w);
  return __builtin_bit_cast(uint32_t, s);
}

// raw region barrier: ds_writes visible, but VMEM loads STAY IN FLIGHT
#define RBAR() { \
    asm volatile("s_waitcnt lgkmcnt(0)" ::: "memory"); \
    __builtin_amdgcn_sched_barrier(0); \
    __builtin_amdgcn_s_barrier(); \
    __builtin_amdgcn_sched_barrier(0); }

// ---- main: 64px strip x 64oc per block, 4 waves, f16 MFMA,
//      software-pipelined with raw barriers (loads cross barriers) ----
__global__ __launch_bounds__(256, 3) void mdconv_main(
    const float* __restrict__ offs, const float* __restrict__ mask,
    const float* __restrict__ bias, const u16* __restrict__ nhwc,
    const u16* __restrict__ wk2, float* __restrict__ out)
{
  __shared__ u16 clds[2][64*PADW];  // 18432 B, double-buffered
  __shared__ int2 pA[576];          //  4608 B  {base, dx|dy<<16}
  __shared__ uint4 pW[576];         //  9216 B  corner weights, packed (h,h) f16x2

  const int tid = threadIdx.x;
  const int lane = tid & 63;
  const int wv = tid >> 6;
  const int b = blockIdx.z;
  const int p = blockIdx.y;
  const int q0 = blockIdx.x * 64;

  // phase 1: per-(k,px) sampling params -> LDS
  for (int item = tid; item < 576; item += 256) {
    const int k = item >> 6;
    const int px = item & 63;
    const int q = q0 + px;
    const int ky = k / 3, kx = k % 3;
    const float oy = offs[((b*18 + 2*k)*HO_ + p)*WO_ + q];
    const float ox = offs[((b*18 + 2*k + 1)*HO_ + p)*WO_ + q];
    const float mm = mask[((b*9 + k)*HO_ + p)*WO_ + q];
    const float py  = (float)(ky + p - 1) + oy;
    const float pxx = (float)(kx + q - 1) + ox;
    const float y0f = floorf(py), x0f = floorf(pxx);
    const int y0 = (int)y0f, x0 = (int)x0f;
    const int y1 = y0 + 1, x1 = x0 + 1;
    const float wy1 = py - y0f, wx1 = pxx - x0f;
    const float wy0 = 1.f - wy1, wx0 = 1.f - wx1;
    const bool vy0 = (y0 >= 0) & (y0 < H_);
    const bool vy1 = (y1 >= 0) & (y1 < H_);
    const bool vx0 = (x0 >= 0) & (x0 < W_);
    const bool vx1 = (x1 >= 0) & (x1 < W_);
    const float w00 = (vy0 & vx0) ? wy0*wx0*mm : 0.f;
    const float w01 = (vy0 & vx1) ? wy0*wx1*mm : 0.f;
    const float w10 = (vy1 & vx0) ? wy1*wx0*mm : 0.f;
    const float w11 = (vy1 & vx1) ? wy1*wx1*mm : 0.f;
    const int y0c = min(max(y0,0),H_-1), y1c = min(max(y1,0),H_-1);
    const int x0c = min(max(x0,0),W_-1), x1c = min(max(x1,0),W_-1);
    // invalid corners have zero weight, so clamped deltas are always safe
    const int dx = (x1c - x0c) * C_;        // 0 or 64
    const int dy = (y1c - y0c) * W_ * C_;   // 0 or 8192
    pA[item] = make_int2(b*HWC_ + (y0c*W_ + x0c)*C_, dx | (dy << 16));
    pW[item] = make_uint4(pkh2(w00), pkh2(w01), pkh2(w10), pkh2(w11));
  }
  __syncthreads();

  f32x4 acc00 = {0.f,0.f,0.f,0.f};
  f32x4 acc01 = acc00, acc10 = acc00, acc11 = acc00;
  const int wr = wv >> 1, wc = wv & 1;
  const int px0 = tid >> 3;          // 0..31 (second item: +32)
  const int c8 = (tid & 7) * 8;      // channel chunk start

  uint4 g0[8], g1[8];                // ping-pong gather state (parity = k&1)
  f16x8 a0[4], a1[4];                // ping-pong A-fragments (parity = k&1)

#define ISSUE_G(kk_, gbuf) { \
    const int piA = (kk_)*64 + px0, piB = piA + 32; \
    const int2 aA = pA[piA]; const int2 aB = pA[piB]; \
    const u16* sA = nhwc + aA.x + c8; \
    const u16* sB = nhwc + aB.x + c8; \
    const int dxA = aA.y & 0xFFFF, dyA = ((uint32_t)aA.y) >> 16; \
    const int dxB = aB.y & 0xFFFF, dyB = ((uint32_t)aB.y) >> 16; \
    gbuf[0] = *(const uint4*)(sA);       gbuf[1] = *(const uint4*)(sA + dxA); \
    gbuf[2] = *(const uint4*)(sA + dyA); gbuf[3] = *(const uint4*)(sA + dyA + dxA); \
    gbuf[4] = *(const uint4*)(sB);       gbuf[5] = *(const uint4*)(sB + dxB); \
    gbuf[6] = *(const uint4*)(sB + dyB); gbuf[7] = *(const uint4*)(sB + dyB + dxB); }

#define LOADA(kk_, areg) { \
    const u16* wg = wk2 + ((kk_)*2 + wr)*2048 + lane*8; \
    areg[0] = *(const f16x8*)(wg);        areg[1] = *(const f16x8*)(wg + 512); \
    areg[2] = *(const f16x8*)(wg + 1024); areg[3] = *(const f16x8*)(wg + 1536); }

#define BLEND_WR(kk_, gbuf) { \
    const int piA = (kk_)*64 + px0, piB = piA + 32; \
    const uint4 wA = pW[piA]; const uint4 wB = pW[piB]; \
    uint4 rA, rB; \
    rA.x = blendh(gbuf[0].x, gbuf[1].x, gbuf[2].x, gbuf[3].x, wA); \
    rA.y = blendh(gbuf[0].y, gbuf[1].y, gbuf[2].y, gbuf[3].y, wA); \
    rA.z = blendh(gbuf[0].z, gbuf[1].z, gbuf[2].z, gbuf[3].z, wA); \
    rA.w = blendh(gbuf[0].w, gbuf[1].w, gbuf[2].w, gbuf[3].w, wA); \
    rB.x = blendh(gbuf[4].x, gbuf[5].x, gbuf[6].x, gbuf[7].x, wB); \
    rB.y = blendh(gbuf[4].y, gbuf[5].y, gbuf[6].y, gbuf[7].y, wB); \
    rB.z = blendh(gbuf[4].z, gbuf[5].z, gbuf[6].z, gbuf[7].z, wB); \
    rB.w = blendh(gbuf[4].w, gbuf[5].w, gbuf[6].w, gbuf[7].w, wB); \
    *(uint4*)(&clds[(kk_)&1][px0*PADW + c8]) = rA; \
    *(uint4*)(&clds[(kk_)&1][(px0+32)*PADW + c8]) = rB; }

#define REGION(k_, GCUR, GNXT, ACUR, ANXT) { \
    const u16* cb = &clds[(k_)&1][(wc*32 + (lane & 15))*PADW + (lane >> 4)*8]; \
    const f16x8 b00 = *(const f16x8*)(cb); \
    const f16x8 b01 = *(const f16x8*)(cb + 32); \
    const f16x8 b10 = *(const f16x8*)(cb + 16*PADW); \
    const f16x8 b11 = *(const f16x8*)(cb + 16*PADW + 32); \
    if ((k_) + 2 <= 8) ISSUE_G((k_)+2, GCUR); \
    if ((k_) + 1 <= 8) LOADA((k_)+1, ANXT); \
    acc00 = __builtin_amdgcn_mfma_f32_16x16x32_f16(ACUR[0], b00, acc00, 0, 0, 0); \
    acc00 = __builtin_amdgcn_mfma_f32_16x16x32_f16(ACUR[1], b01, acc00, 0, 0, 0); \
    acc01 = __builtin_amdgcn_mfma_f32_16x16x32_f16(ACUR[0], b10, acc01, 0, 0, 0); \
    acc01 = __builtin_amdgcn_mfma_f32_16x16x32_f16(ACUR[1], b11, acc01, 0, 0, 0); \
    acc10 = __builtin_amdgcn_mfma_f32_16x16x32_f16(ACUR[2], b00, acc10, 0, 0, 0); \
    acc10 = __builtin_amdgcn_mfma_f32_16x16x32_f16(ACUR[3], b01, acc10, 0, 0, 0); \
    acc11 = __builtin_amdgcn_mfma_f32_16x16x32_f16(ACUR[2], b10, acc11, 0, 0, 0); \
    acc11 = __builtin_amdgcn_mfma_f32_16x16x32_f16(ACUR[3], b11, acc11, 0, 0, 0); \
    if ((k_) + 1 <= 8) { BLEND_WR((k_)+1, GNXT); RBAR(); } }

  // prologue: fill the pipe (latency exposed once)
  ISSUE_G(0, g0);
  ISSUE_G(1, g1);
  LOADA(0, a0);
  BLEND_WR(0, g0);
  RBAR();

  REGION(0, g0, g1, a0, a1);
  REGION(1, g1, g0, a1, a0);
  REGION(2, g0, g1, a0, a1);
  REGION(3, g1, g0, a1, a0);
  REGION(4, g0, g1, a0, a1);
  REGION(5, g1, g0, a1, a0);
  REGION(6, g0, g1, a0, a1);
  REGION(7, g1, g0, a1, a0);
  REGION(8, g0, g1, a0, a1);

  // epilogue: C/D layout col=lane&15 (px), row=(lane>>4)*4+j (oc)
  const int qc = q0 + wc*32 + (lane & 15);
  const int ocr = wr*32 + (lane >> 4)*4;
  #pragma unroll
  for (int m = 0; m < 2; ++m) {
    #pragma unroll
    for (int n = 0; n < 2; ++n) {
      const f32x4 a = (m==0) ? (n==0 ? acc00 : acc01) : (n==0 ? acc10 : acc11);
      #pragma unroll
      for (int j = 0; j < 4; ++j) {
        const int oc = ocr + m*16 + j;
        out[((b*OC_ + oc)*HO_ + p)*WO_ + qc + n*16] = a[j] + bias[oc];
      }
    }
  }
}

extern "C" void kernel_launch(void* const* d_in, const int* in_sizes, int n_in,
                              void* d_out, int out_size, void* d_ws, size_t ws_size,
                              hipStream_t stream) {
  const float* input  = (const float*)d_in[0];
  const float* offset = (const float*)d_in[1];
  const float* mask   = (const float*)d_in[2];
  const float* weight = (const float*)d_in[3];
  const float* bias   = (const float*)d_in[4];
  float* out = (float*)d_out;

  u16* nhwc = (u16*)d_ws;                              // 16 MB
  u16* wk2  = nhwc + (size_t)B_*H_*W_*C_;              // 72 KB

  hipLaunchKernelGGL(wprep_kernel, dim3(144), dim3(256), 0, stream, weight, wk2);
  hipLaunchKernelGGL(nhwc_kernel, dim3(2, 128, 8), dim3(256), 0, stream, input, nhwc);
  hipLaunchKernelGGL(mdconv_main, dim3(2, 128, 8), dim3(256), 0, stream,
                     offset, mask, bias, nhwc, wk2, out);
}